// Round 4
// baseline (4493.577 us; speedup 1.0000x reference)
//
#include <hip/hip_runtime.h>

constexpr int N = 8192;
constexpr int D = 256;

typedef __attribute__((ext_vector_type(8))) short short8v;
typedef __attribute__((ext_vector_type(4))) short short4v;
typedef __attribute__((ext_vector_type(4))) float f32x4;

__device__ __forceinline__ const float4* f4c(const float* p) { return reinterpret_cast<const float4*>(p); }
__device__ __forceinline__ float4* f4(float* p) { return reinterpret_cast<float4*>(p); }

__device__ __forceinline__ short f2bf(float f) {
    unsigned u = __builtin_bit_cast(unsigned, f);
    u += 0x7fff + ((u >> 16) & 1);
    return (short)(u >> 16);
}
__device__ __forceinline__ float bf2f(short s) {
    unsigned u = ((unsigned)(unsigned short)s) << 16;
    return __builtin_bit_cast(float, u);
}
template <int NS>
__device__ __forceinline__ void splitN(float x, short* s) {
    s[0] = f2bf(x);
    if constexpr (NS > 1) {
        float r = x - bf2f(s[0]);
        s[1] = f2bf(r);
        s[2] = f2bf(r - bf2f(s[1]));
    }
}

// ===========================================================================
// Sparse aggregation path: alpha (post-softmax) is >99% exact zeros because
// exp underflows >87 below the row max. Scan rows, accumulate only nonzeros.
// out[row, 0:256] = sum_j M[row,j]*H[j,:]; out[row, 256:512] = sum_j M[row,j]*Dp[j,:]
// One wave per row; ballot over 256 values/iter; cooperative X-row loads.
// Deterministic: fixed (it, e, lane) summation order.
// ===========================================================================
__global__ __launch_bounds__(256) void spmm_scan(const float* __restrict__ M,
                                                 const float* __restrict__ H,
                                                 const float* __restrict__ Dp,
                                                 float* __restrict__ out) {
    const int wave = threadIdx.x >> 6;
    const int lane = threadIdx.x & 63;
    const int row = blockIdx.x * 4 + wave;
    const float* __restrict__ src = (lane < 32) ? H : Dp;
    const int c0 = (lane & 31) * 8;
    const float4* rp = f4c(M + (size_t)row * N);
    float4 acc0 = {0.f, 0.f, 0.f, 0.f}, acc1 = {0.f, 0.f, 0.f, 0.f};
#pragma unroll 1
    for (int it = 0; it < N / 256; ++it) {
        float4 v = rp[it * 64 + lane];
        float va[4] = {v.x, v.y, v.z, v.w};
#pragma unroll
        for (int e = 0; e < 4; ++e) {
            unsigned long long mask = __ballot(va[e] != 0.0f);
            while (mask) {
                int l = __builtin_ctzll(mask);
                mask &= mask - 1;
                float a = __shfl(va[e], l);
                int j = it * 256 + l * 4 + e;
                const float* xr = src + (size_t)j * D + c0;
                float4 x0 = *f4c(xr);
                float4 x1 = *f4c(xr + 4);
                acc0.x = fmaf(a, x0.x, acc0.x);
                acc0.y = fmaf(a, x0.y, acc0.y);
                acc0.z = fmaf(a, x0.z, acc0.z);
                acc0.w = fmaf(a, x0.w, acc0.w);
                acc1.x = fmaf(a, x1.x, acc1.x);
                acc1.y = fmaf(a, x1.y, acc1.y);
                acc1.z = fmaf(a, x1.z, acc1.z);
                acc1.w = fmaf(a, x1.w, acc1.w);
            }
        }
    }
    float* orow = out + (size_t)row * 512 + ((lane < 32) ? c0 : 256 + c0);
    f4(orow)[0] = acc0;
    f4(orow)[1] = acc1;
}

// 64x64 LDS tile transpose: outT[j][i] = in[i][j]
__global__ __launch_bounds__(256) void transpose_kernel(const float* __restrict__ in,
                                                        float* __restrict__ outT) {
    __shared__ float tile[64][65];
    const int t = threadIdx.x;
    const int i0 = blockIdx.y * 64;
    const int j0 = blockIdx.x * 64;
    const int r = t >> 2;
    const int c0 = (t & 3) * 16;
#pragma unroll
    for (int q = 0; q < 4; q++) {
        float4 v = *f4c(in + (size_t)(i0 + r) * N + j0 + c0 + q * 4);
        tile[r][c0 + q * 4 + 0] = v.x;
        tile[r][c0 + q * 4 + 1] = v.y;
        tile[r][c0 + q * 4 + 2] = v.z;
        tile[r][c0 + q * 4 + 3] = v.w;
    }
    __syncthreads();
#pragma unroll
    for (int q = 0; q < 4; q++) {
        float4 o = {tile[c0 + q * 4 + 0][r], tile[c0 + q * 4 + 1][r],
                    tile[c0 + q * 4 + 2][r], tile[c0 + q * 4 + 3][r]};
        *f4(outT + (size_t)(j0 + r) * N + i0 + c0 + q * 4) = o;
    }
}

// ===========================================================================
// FALLBACK (round-2 proven): in-kernel split dense agg via MFMA
// ===========================================================================
template <int NTERMS, int TRANS>
__global__ __launch_bounds__(256, NTERMS == 1 ? 3 : 2)
void agg_mfma(const float* __restrict__ alpha, const float* __restrict__ H,
              const float* __restrict__ Dp, float* __restrict__ out) {
    constexpr int NS = (NTERMS == 1) ? 1 : 3;
    __shared__ short As[NS][128][40];
    __shared__ short Bs[NS][128][40];
    const int t = threadIdx.x;
    const int bx = blockIdx.x;
    const int i0 = blockIdx.y * 128;
    const float* Bsrc = (bx < 2) ? (H + bx * 128) : (Dp + (bx - 2) * 128);
    const int lane = t & 63;
    const int w = t >> 6;
    const int wm = w >> 1, wn = w & 1;
    const int fr = lane & 15, fq = lane >> 4;
    f32x4 acc[4][4];
#pragma unroll
    for (int a = 0; a < 4; a++)
#pragma unroll
        for (int b = 0; b < 4; b++) acc[a][b] = (f32x4){0.f, 0.f, 0.f, 0.f};
    const int sm = t >> 1;
    const int skh = (t & 1) << 4;
    const int skk = t >> 3;
    const int sc0 = (t & 7) << 4;
#pragma unroll 1
    for (int k0 = 0; k0 < N; k0 += 32) {
        if constexpr (TRANS == 0) {
            const float* src = alpha + (size_t)(i0 + sm) * N + k0 + skh;
            const int swz = (sm >> 4) & 3;
#pragma unroll
            for (int q = 0; q < 4; q++) {
                float4 v = f4c(src)[q];
                int k = skh + 4 * q;
                int col = ((((k >> 3) ^ swz)) << 3) | (k & 4);
                float vv[4] = {v.x, v.y, v.z, v.w};
                short a0[4], a1[4], a2[4];
#pragma unroll
                for (int e = 0; e < 4; e++) {
                    short tmp[3];
                    splitN<NS>(vv[e], tmp);
                    a0[e] = tmp[0]; a1[e] = tmp[1]; a2[e] = tmp[2];
                }
                *(short4v*)&As[0][sm][col] = (short4v){a0[0], a0[1], a0[2], a0[3]};
                if constexpr (NTERMS > 1) {
                    *(short4v*)&As[1][sm][col] = (short4v){a1[0], a1[1], a1[2], a1[3]};
                    *(short4v*)&As[2][sm][col] = (short4v){a2[0], a2[1], a2[2], a2[3]};
                }
            }
        } else {
            const float* src = alpha + (size_t)(k0 + skk) * N + i0 + sc0;
#pragma unroll
            for (int q = 0; q < 4; q++) {
                float4 v = f4c(src)[q];
                float vv[4] = {v.x, v.y, v.z, v.w};
#pragma unroll
                for (int e = 0; e < 4; e++) {
                    int m = sc0 + 4 * q + e;
                    int swz = (m >> 4) & 3;
                    int col = (skk & 7) | ((((skk >> 3) ^ swz)) << 3);
                    short tmp[3];
                    splitN<NS>(vv[e], tmp);
                    As[0][m][col] = tmp[0];
                    if constexpr (NTERMS > 1) { As[1][m][col] = tmp[1]; As[2][m][col] = tmp[2]; }
                }
            }
        }
        {
            const float* src = Bsrc + (size_t)(k0 + skk) * D + sc0;
#pragma unroll
            for (int q = 0; q < 4; q++) {
                float4 v = f4c(src)[q];
                float vv[4] = {v.x, v.y, v.z, v.w};
#pragma unroll
                for (int e = 0; e < 4; e++) {
                    int n = sc0 + 4 * q + e;
                    int swz = (n >> 4) & 3;
                    int col = (skk & 7) | ((((skk >> 3) ^ swz)) << 3);
                    short tmp[3];
                    splitN<NS>(vv[e], tmp);
                    Bs[0][n][col] = tmp[0];
                    if constexpr (NTERMS > 1) { Bs[1][n][col] = tmp[1]; Bs[2][n][col] = tmp[2]; }
                }
            }
        }
        __syncthreads();
        short8v af[NS][4], bg[NS][4];
#pragma unroll
        for (int mr = 0; mr < 4; mr++) {
            int row = wm * 64 + mr * 16 + fr;
            int cidx = 8 * (fq ^ ((wm * 4 + mr) & 3));
#pragma unroll
            for (int s = 0; s < NS; s++) af[s][mr] = *(const short8v*)&As[s][row][cidx];
        }
#pragma unroll
        for (int nr = 0; nr < 4; nr++) {
            int rowb = wn * 64 + nr * 16 + fr;
            int cidx = 8 * (fq ^ ((wn * 4 + nr) & 3));
#pragma unroll
            for (int s = 0; s < NS; s++) bg[s][nr] = *(const short8v*)&Bs[s][rowb][cidx];
        }
#pragma unroll
        for (int mr = 0; mr < 4; mr++) {
#pragma unroll
            for (int nr = 0; nr < 4; nr++) {
                f32x4 a = acc[mr][nr];
                a = __builtin_amdgcn_mfma_f32_16x16x32_bf16(af[0][mr], bg[0][nr], a, 0, 0, 0);
                if constexpr (NTERMS > 1) {
                    a = __builtin_amdgcn_mfma_f32_16x16x32_bf16(af[0][mr], bg[1][nr], a, 0, 0, 0);
                    a = __builtin_amdgcn_mfma_f32_16x16x32_bf16(af[1][mr], bg[0][nr], a, 0, 0, 0);
                    a = __builtin_amdgcn_mfma_f32_16x16x32_bf16(af[1][mr], bg[1][nr], a, 0, 0, 0);
                    a = __builtin_amdgcn_mfma_f32_16x16x32_bf16(af[0][mr], bg[2][nr], a, 0, 0, 0);
                    a = __builtin_amdgcn_mfma_f32_16x16x32_bf16(af[2][mr], bg[0][nr], a, 0, 0, 0);
                }
                acc[mr][nr] = a;
            }
        }
        __syncthreads();
    }
#pragma unroll
    for (int mr = 0; mr < 4; mr++) {
#pragma unroll
        for (int nr = 0; nr < 4; nr++) {
            int col = bx * 128 + wn * 64 + nr * 16 + fr;
#pragma unroll
            for (int j = 0; j < 4; j++) {
                int row = i0 + wm * 64 + mr * 16 + fq * 4 + j;
                out[(size_t)row * 512 + col] = acc[mr][nr][j];
            }
        }
    }
}

// ---------------------------------------------------------------------------
__global__ __launch_bounds__(256) void rowdot_kernel(const float* __restrict__ X,
                                                     const float* __restrict__ v,
                                                     float* __restrict__ out) {
    int lane = threadIdx.x & 63;
    int row = blockIdx.x * 4 + (threadIdx.x >> 6);
    float4 a = f4c(X + (size_t)row * D)[lane];
    float4 b = f4c(v)[lane];
    float s = a.x * b.x + a.y * b.y + a.z * b.z + a.w * b.w;
#pragma unroll
    for (int off = 32; off > 0; off >>= 1) s += __shfl_down(s, off);
    if (lane == 0) out[row] = s;
}

__global__ __launch_bounds__(256) void gemm_nk256_kernel(const float* __restrict__ A,
                                                         const float* __restrict__ W,
                                                         float* __restrict__ C) {
    __shared__ float As[16][68];
    __shared__ float Bs[16][68];
    int t = threadIdx.x;
    int tx = t & 15, ty = t >> 4;
    int j0 = blockIdx.x * 64;
    int i0 = blockIdx.y * 64;
    float acc[4][4] = {};
    for (int k0 = 0; k0 < 256; k0 += 16) {
        {
            int m = t >> 2, k4 = (t & 3) * 4;
            float4 a = *f4c(A + (size_t)(i0 + m) * D + k0 + k4);
            As[k4 + 0][m] = a.x; As[k4 + 1][m] = a.y; As[k4 + 2][m] = a.z; As[k4 + 3][m] = a.w;
            int kk = t >> 4, c = (t & 15) * 4;
            *f4(&Bs[kk][c]) = *f4c(W + (size_t)(k0 + kk) * D + j0 + c);
        }
        __syncthreads();
#pragma unroll
        for (int kk = 0; kk < 16; kk++) {
            float4 av = *f4c(&As[kk][ty * 4]);
            float4 bv = *f4c(&Bs[kk][tx * 4]);
            float a[4] = {av.x, av.y, av.z, av.w};
            float b[4] = {bv.x, bv.y, bv.z, bv.w};
#pragma unroll
            for (int r = 0; r < 4; r++)
#pragma unroll
                for (int c = 0; c < 4; c++) acc[r][c] = fmaf(a[r], b[c], acc[r][c]);
        }
        __syncthreads();
    }
#pragma unroll
    for (int r = 0; r < 4; r++) {
        float4 o = {acc[r][0], acc[r][1], acc[r][2], acc[r][3]};
        *f4(C + (size_t)(i0 + ty * 4 + r) * D + j0 + tx * 4) = o;
    }
}

__global__ __launch_bounds__(256) void update_kernel(const float* __restrict__ A1,
                                                     const float* __restrict__ W1,
                                                     const float* __restrict__ A2,
                                                     const float* __restrict__ W2,
                                                     float* __restrict__ C) {
    __shared__ float As[16][68];
    __shared__ float Bs[16][68];
    int t = threadIdx.x;
    int tx = t & 15, ty = t >> 4;
    int j0 = blockIdx.x * 64;
    int i0 = blockIdx.y * 64;
    float acc[4][4] = {};
#pragma unroll 1
    for (int pass = 0; pass < 2; pass++) {
        const float* Ap = pass ? A2 : A1;
        const float* Wp = pass ? W2 : W1;
        for (int k0 = 0; k0 < 256; k0 += 16) {
            {
                int m = t >> 2, k4 = (t & 3) * 4;
                float4 a = *f4c(Ap + (size_t)(i0 + m) * D + k0 + k4);
                As[k4 + 0][m] = a.x; As[k4 + 1][m] = a.y; As[k4 + 2][m] = a.z; As[k4 + 3][m] = a.w;
                int kk = t >> 4, c = (t & 15) * 4;
                *f4(&Bs[kk][c]) = *f4c(Wp + (size_t)(k0 + kk) * D + j0 + c);
            }
            __syncthreads();
#pragma unroll
            for (int kk = 0; kk < 16; kk++) {
                float4 av = *f4c(&As[kk][ty * 4]);
                float4 bv = *f4c(&Bs[kk][tx * 4]);
                float a[4] = {av.x, av.y, av.z, av.w};
                float b[4] = {bv.x, bv.y, bv.z, bv.w};
#pragma unroll
                for (int r = 0; r < 4; r++)
#pragma unroll
                    for (int c = 0; c < 4; c++) acc[r][c] = fmaf(a[r], b[c], acc[r][c]);
            }
            __syncthreads();
        }
    }
#pragma unroll
    for (int r = 0; r < 4; r++) {
        float o[4];
#pragma unroll
        for (int c = 0; c < 4; c++) {
            float x = acc[r][c];
            o[c] = x >= 0.f ? x : 0.1f * x;
        }
        float4 ov = {o[0], o[1], o[2], o[3]};
        *f4(C + (size_t)(i0 + ty * 4 + r) * D + j0 + tx * 4) = ov;
    }
}

__global__ __launch_bounds__(256) void logits_kernel(const float* __restrict__ Z,
                                                     const float* __restrict__ Dp,
                                                     const float* __restrict__ bh,
                                                     const float* __restrict__ bd,
                                                     float* __restrict__ alpha) {
    __shared__ float As[32][132];
    __shared__ float Bs[32][132];
    int t = threadIdx.x;
    int tx = t & 15, ty = t >> 4;
    int j0 = blockIdx.x * 128;
    int i0 = blockIdx.y * 128;
    float acc[8][8] = {};
    for (int k0 = 0; k0 < 256; k0 += 32) {
#pragma unroll
        for (int r = 0; r < 4; r++) {
            int fid = r * 256 + t;
            int m = fid >> 3, k4 = (fid & 7) * 4;
            float4 a = *f4c(Z + (size_t)(i0 + m) * D + k0 + k4);
            As[k4 + 0][m] = a.x; As[k4 + 1][m] = a.y; As[k4 + 2][m] = a.z; As[k4 + 3][m] = a.w;
            float4 b = *f4c(Dp + (size_t)(j0 + m) * D + k0 + k4);
            Bs[k4 + 0][m] = b.x; Bs[k4 + 1][m] = b.y; Bs[k4 + 2][m] = b.z; Bs[k4 + 3][m] = b.w;
        }
        __syncthreads();
#pragma unroll 4
        for (int kk = 0; kk < 32; kk++) {
            float4 a0 = *f4c(&As[kk][ty * 8]);
            float4 a1 = *f4c(&As[kk][ty * 8 + 4]);
            float4 b0 = *f4c(&Bs[kk][tx * 8]);
            float4 b1 = *f4c(&Bs[kk][tx * 8 + 4]);
            float a[8] = {a0.x, a0.y, a0.z, a0.w, a1.x, a1.y, a1.z, a1.w};
            float b[8] = {b0.x, b0.y, b0.z, b0.w, b1.x, b1.y, b1.z, b1.w};
#pragma unroll
            for (int r = 0; r < 8; r++)
#pragma unroll
                for (int c = 0; c < 8; c++) acc[r][c] = fmaf(a[r], b[c], acc[r][c]);
        }
        __syncthreads();
    }
    float4 bd0 = *f4c(bd + j0 + tx * 8);
    float4 bd1 = *f4c(bd + j0 + tx * 8 + 4);
#pragma unroll
    for (int r = 0; r < 8; r++) {
        float bhr = bh[i0 + ty * 8 + r];
        float4 o0 = {acc[r][0] + bhr + bd0.x, acc[r][1] + bhr + bd0.y,
                     acc[r][2] + bhr + bd0.z, acc[r][3] + bhr + bd0.w};
        float4 o1 = {acc[r][4] + bhr + bd1.x, acc[r][5] + bhr + bd1.y,
                     acc[r][6] + bhr + bd1.z, acc[r][7] + bhr + bd1.w};
        float* orow = alpha + (size_t)(i0 + ty * 8 + r) * N + j0 + tx * 8;
        f4(orow)[0] = o0;
        f4(orow)[1] = o1;
    }
}

__global__ __launch_bounds__(256) void softmax_kernel(float* __restrict__ alpha) {
    int row = blockIdx.x;
    int t = threadIdx.x;
    float4* rp = f4(alpha + (size_t)row * N);
    float4 v[8];
    float m = -3.4e38f;
#pragma unroll
    for (int i = 0; i < 8; i++) {
        v[i] = rp[i * 256 + t];
        m = fmaxf(m, fmaxf(fmaxf(v[i].x, v[i].y), fmaxf(v[i].z, v[i].w)));
    }
    __shared__ float red[8];
#pragma unroll
    for (int off = 32; off > 0; off >>= 1) m = fmaxf(m, __shfl_xor(m, off));
    if ((t & 63) == 0) red[t >> 6] = m;
    __syncthreads();
    m = fmaxf(fmaxf(red[0], red[1]), fmaxf(red[2], red[3]));
    float s = 0.f;
#pragma unroll
    for (int i = 0; i < 8; i++) {
        v[i].x = __expf(v[i].x - m);
        v[i].y = __expf(v[i].y - m);
        v[i].z = __expf(v[i].z - m);
        v[i].w = __expf(v[i].w - m);
        s += v[i].x + v[i].y + v[i].z + v[i].w;
    }
#pragma unroll
    for (int off = 32; off > 0; off >>= 1) s += __shfl_xor(s, off);
    if ((t & 63) == 0) red[4 + (t >> 6)] = s;
    __syncthreads();
    s = red[4] + red[5] + red[6] + red[7];
    float inv = 1.f / s;
#pragma unroll
    for (int i = 0; i < 8; i++) {
        v[i].x *= inv; v[i].y *= inv; v[i].z *= inv; v[i].w *= inv;
        rp[i * 256 + t] = v[i];
    }
}

__global__ __launch_bounds__(256) void diag_kernel(const float* __restrict__ alpha,
                                                   float* __restrict__ da) {
    int i = blockIdx.x * 256 + threadIdx.x;
    da[i] = alpha[(size_t)i * N + i];
}

__global__ __launch_bounds__(256) void combine_kernel(const float* __restrict__ S,
                                                      const float* __restrict__ T,
                                                      const float* __restrict__ da,
                                                      const float* __restrict__ H,
                                                      const float* __restrict__ Dp,
                                                      float* __restrict__ hagg,
                                                      float* __restrict__ dagg) {
    int gid = blockIdx.x * 256 + threadIdx.x;
    int i = gid >> 6;
    int d4 = (gid & 63) * 4;
    float a = da[i];
    float4 sH = *f4c(S + (size_t)i * (2 * D) + d4);
    float4 sD = *f4c(S + (size_t)i * (2 * D) + D + d4);
    float4 tH = *f4c(T + (size_t)i * (2 * D) + d4);
    float4 tD = *f4c(T + (size_t)i * (2 * D) + D + d4);
    float4 h = *f4c(H + (size_t)i * D + d4);
    float4 dp = *f4c(Dp + (size_t)i * D + d4);
    float4 hd = {h.x + dp.x, h.y + dp.y, h.z + dp.z, h.w + dp.w};
    float4 ha = {tH.x + sD.x - a * hd.x, tH.y + sD.y - a * hd.y,
                 tH.z + sD.z - a * hd.z, tH.w + sD.w - a * hd.w};
    float4 dg = {sH.x + tD.x - a * hd.x, sH.y + tD.y - a * hd.y,
                 sH.z + tD.z - a * hd.z, sH.w + tD.w - a * hd.w};
    *f4(hagg + (size_t)i * D + d4) = ha;
    *f4(dagg + (size_t)i * D + d4) = dg;
}

extern "C" void kernel_launch(void* const* d_in, const int* in_sizes, int n_in,
                              void* d_out, int out_size, void* d_ws, size_t ws_size,
                              hipStream_t stream) {
    const float* head = (const float*)d_in[0];
    const float* dep = (const float*)d_in[1];
    const float* tpA[2] = {(const float*)d_in[2], (const float*)d_in[5]};
    const float* tpb1[2] = {(const float*)d_in[3], (const float*)d_in[6]};
    const float* tpb2[2] = {(const float*)d_in[4], (const float*)d_in[7]};
    const float* awh[2] = {(const float*)d_in[8], (const float*)d_in[12]};
    const float* awd[2] = {(const float*)d_in[9], (const float*)d_in[13]};
    const float* cwh[2] = {(const float*)d_in[10], (const float*)d_in[14]};
    const float* cwd[2] = {(const float*)d_in[11], (const float*)d_in[15]};

    float* out = (float*)d_out;
    float* outHead = out;
    float* outDep = out + (size_t)N * D;
    float* alpha1 = out + (size_t)2 * N * D;
    float* alpha2 = alpha1 + (size_t)N * N;

    float* w = (float*)d_ws;
    float* S = w;               w += (size_t)N * 2 * D;
    float* Z = S;               // overlay, disjoint lifetime
    float* T = w;               w += (size_t)N * 2 * D;
    float* bh = w;              w += N;
    float* bd = w;              w += N;
    float* da = w;              w += N;
    float* hagg = w;            w += (size_t)N * D;
    float* dagg = w;            w += (size_t)N * D;
    float* H1 = w;              w += (size_t)N * D;
    float* D1 = w;              w += (size_t)N * D;
    float* alphaT = w;          w += (size_t)N * N;
    size_t needed = ((char*)w) - (char*)d_ws;
    const bool use_sparse = (ws_size >= needed);

    for (int L = 0; L < 2; L++) {
        const float* Hin = L ? H1 : head;
        const float* Din = L ? D1 : dep;
        float* Hout = L ? outHead : H1;
        float* Dout = L ? outDep : D1;
        float* alpha = L ? alpha2 : alpha1;

        rowdot_kernel<<<N / 4, 256, 0, stream>>>(Hin, tpb1[L], bh);
        rowdot_kernel<<<N / 4, 256, 0, stream>>>(Din, tpb2[L], bd);
        gemm_nk256_kernel<<<dim3(D / 64, N / 64), 256, 0, stream>>>(Hin, tpA[L], Z);
        logits_kernel<<<dim3(N / 128, N / 128), 256, 0, stream>>>(Z, Din, bh, bd, alpha);
        softmax_kernel<<<N, 256, 0, stream>>>(alpha);
        diag_kernel<<<N / 256, 256, 0, stream>>>(alpha, da);
        if (use_sparse) {
            transpose_kernel<<<dim3(N / 64, N / 64), 256, 0, stream>>>(alpha, alphaT);
            spmm_scan<<<N / 4, 256, 0, stream>>>(alpha, Hin, Din, S);
            spmm_scan<<<N / 4, 256, 0, stream>>>(alphaT, Hin, Din, T);
        } else {
            if (L == 0) {
                agg_mfma<6, 0><<<dim3(4, N / 128), 256, 0, stream>>>(alpha, Hin, Din, S);
                agg_mfma<6, 1><<<dim3(4, N / 128), 256, 0, stream>>>(alpha, Hin, Din, T);
            } else {
                agg_mfma<1, 0><<<dim3(4, N / 128), 256, 0, stream>>>(alpha, Hin, Din, S);
                agg_mfma<1, 1><<<dim3(4, N / 128), 256, 0, stream>>>(alpha, Hin, Din, T);
            }
        }
        combine_kernel<<<(N * D / 4) / 256, 256, 0, stream>>>(S, T, da, Hin, Din, hagg, dagg);
        update_kernel<<<dim3(D / 64, N / 64), 256, 0, stream>>>(hagg, awh[L], Hin, cwh[L], Hout);
        update_kernel<<<dim3(D / 64, N / 64), 256, 0, stream>>>(dagg, awd[L], Din, cwd[L], Dout);
    }
}

// Round 5
// 2041.014 us; speedup vs baseline: 2.2016x; 2.2016x over previous
//
#include <hip/hip_runtime.h>

constexpr int N = 8192;
constexpr int D = 256;

typedef __attribute__((ext_vector_type(8))) short short8v;
typedef __attribute__((ext_vector_type(4))) short short4v;
typedef __attribute__((ext_vector_type(4))) float f32x4;

__device__ __forceinline__ const float4* f4c(const float* p) { return reinterpret_cast<const float4*>(p); }
__device__ __forceinline__ float4* f4(float* p) { return reinterpret_cast<float4*>(p); }

__device__ __forceinline__ short f2bf(float f) {
    unsigned u = __builtin_bit_cast(unsigned, f);
    u += 0x7fff + ((u >> 16) & 1);
    return (short)(u >> 16);
}
__device__ __forceinline__ float bf2f(short s) {
    unsigned u = ((unsigned)(unsigned short)s) << 16;
    return __builtin_bit_cast(float, u);
}
template <int NS>
__device__ __forceinline__ void splitN(float x, short* s) {
    s[0] = f2bf(x);
    if constexpr (NS > 1) {
        float r = x - bf2f(s[0]);
        s[1] = f2bf(r);
        s[2] = f2bf(r - bf2f(s[1]));
    }
}

// ===========================================================================
// Sparse aggregation, v2. alpha post-softmax is >99% exact zeros (exp
// underflow + v_exp ftz). One block = one output row; 8 waves each scan a
// disjoint 4KB segment of the M-row with 4 preloaded float4s (deep MLP),
// process nonzeros from ballots, then deterministic LDS reduction.
//   blockIdx.y = 0: out=S, M=alpha ; blockIdx.y = 1: out=T, M=alphaT
//   out[row, 0:256] = sum_j M[row,j]*H[j,:]; out[row,256:512] = ..*Dp[j,:]
// ===========================================================================
__global__ __launch_bounds__(512) void spmm_scan8(const float* __restrict__ M0,
                                                  const float* __restrict__ M1,
                                                  const float* __restrict__ H,
                                                  const float* __restrict__ Dp,
                                                  float* __restrict__ S,
                                                  float* __restrict__ T) {
    const float* __restrict__ M = blockIdx.y ? M1 : M0;
    float* __restrict__ out = blockIdx.y ? T : S;
    const int row = blockIdx.x;
    const int w = threadIdx.x >> 6;
    const int lane = threadIdx.x & 63;
    const float* __restrict__ src = (lane < 32) ? H : Dp;
    const int c0 = (lane & 31) * 8;

    // preload this wave's 4KB segment (4 independent 1KB wave-loads)
    const float4* rp = f4c(M + (size_t)row * N) + w * 256;
    float4 v[4];
#pragma unroll
    for (int q = 0; q < 4; q++) v[q] = rp[q * 64 + lane];

    float4 acc0 = {0.f, 0.f, 0.f, 0.f}, acc1 = {0.f, 0.f, 0.f, 0.f};
#pragma unroll
    for (int q = 0; q < 4; q++) {
        float va[4] = {v[q].x, v[q].y, v[q].z, v[q].w};
#pragma unroll
        for (int e = 0; e < 4; e++) {
            unsigned long long mask = __ballot(va[e] != 0.0f);
            while (mask) {
                int l = __builtin_ctzll(mask);
                mask &= mask - 1;
                float a = __shfl(va[e], l);
                int j = w * 1024 + q * 256 + l * 4 + e;
                const float* xr = src + (size_t)j * D + c0;
                float4 x0 = *f4c(xr);
                float4 x1 = *f4c(xr + 4);
                acc0.x = fmaf(a, x0.x, acc0.x);
                acc0.y = fmaf(a, x0.y, acc0.y);
                acc0.z = fmaf(a, x0.z, acc0.z);
                acc0.w = fmaf(a, x0.w, acc0.w);
                acc1.x = fmaf(a, x1.x, acc1.x);
                acc1.y = fmaf(a, x1.y, acc1.y);
                acc1.z = fmaf(a, x1.z, acc1.z);
                acc1.w = fmaf(a, x1.w, acc1.w);
            }
        }
    }

    __shared__ float part[8][512];
    const int colbase = c0 + ((lane < 32) ? 0 : 256);
    *f4(&part[w][colbase]) = acc0;
    *f4(&part[w][colbase + 4]) = acc1;
    __syncthreads();
    const int t = threadIdx.x;
    float s = 0.f;
#pragma unroll
    for (int ww = 0; ww < 8; ww++) s += part[ww][t];
    out[(size_t)row * 512 + t] = s;
}

// 64x64 LDS tile transpose: outT[j][i] = in[i][j]
__global__ __launch_bounds__(256) void transpose_kernel(const float* __restrict__ in,
                                                        float* __restrict__ outT) {
    __shared__ float tile[64][65];
    const int t = threadIdx.x;
    const int i0 = blockIdx.y * 64;
    const int j0 = blockIdx.x * 64;
    const int r = t >> 2;
    const int c0 = (t & 3) * 16;
#pragma unroll
    for (int q = 0; q < 4; q++) {
        float4 v = *f4c(in + (size_t)(i0 + r) * N + j0 + c0 + q * 4);
        tile[r][c0 + q * 4 + 0] = v.x;
        tile[r][c0 + q * 4 + 1] = v.y;
        tile[r][c0 + q * 4 + 2] = v.z;
        tile[r][c0 + q * 4 + 3] = v.w;
    }
    __syncthreads();
#pragma unroll
    for (int q = 0; q < 4; q++) {
        float4 o = {tile[c0 + q * 4 + 0][r], tile[c0 + q * 4 + 1][r],
                    tile[c0 + q * 4 + 2][r], tile[c0 + q * 4 + 3][r]};
        *f4(outT + (size_t)(j0 + r) * N + i0 + c0 + q * 4) = o;
    }
}

// ===========================================================================
// FALLBACK (round-2 proven): in-kernel split dense agg via MFMA
// ===========================================================================
template <int NTERMS, int TRANS>
__global__ __launch_bounds__(256, NTERMS == 1 ? 3 : 2)
void agg_mfma(const float* __restrict__ alpha, const float* __restrict__ H,
              const float* __restrict__ Dp, float* __restrict__ out) {
    constexpr int NS = (NTERMS == 1) ? 1 : 3;
    __shared__ short As[NS][128][40];
    __shared__ short Bs[NS][128][40];
    const int t = threadIdx.x;
    const int bx = blockIdx.x;
    const int i0 = blockIdx.y * 128;
    const float* Bsrc = (bx < 2) ? (H + bx * 128) : (Dp + (bx - 2) * 128);
    const int lane = t & 63;
    const int w = t >> 6;
    const int wm = w >> 1, wn = w & 1;
    const int fr = lane & 15, fq = lane >> 4;
    f32x4 acc[4][4];
#pragma unroll
    for (int a = 0; a < 4; a++)
#pragma unroll
        for (int b = 0; b < 4; b++) acc[a][b] = (f32x4){0.f, 0.f, 0.f, 0.f};
    const int sm = t >> 1;
    const int skh = (t & 1) << 4;
    const int skk = t >> 3;
    const int sc0 = (t & 7) << 4;
#pragma unroll 1
    for (int k0 = 0; k0 < N; k0 += 32) {
        if constexpr (TRANS == 0) {
            const float* src = alpha + (size_t)(i0 + sm) * N + k0 + skh;
            const int swz = (sm >> 4) & 3;
#pragma unroll
            for (int q = 0; q < 4; q++) {
                float4 v = f4c(src)[q];
                int k = skh + 4 * q;
                int col = ((((k >> 3) ^ swz)) << 3) | (k & 4);
                float vv[4] = {v.x, v.y, v.z, v.w};
                short a0[4], a1[4], a2[4];
#pragma unroll
                for (int e = 0; e < 4; e++) {
                    short tmp[3];
                    splitN<NS>(vv[e], tmp);
                    a0[e] = tmp[0]; a1[e] = tmp[1]; a2[e] = tmp[2];
                }
                *(short4v*)&As[0][sm][col] = (short4v){a0[0], a0[1], a0[2], a0[3]};
                if constexpr (NTERMS > 1) {
                    *(short4v*)&As[1][sm][col] = (short4v){a1[0], a1[1], a1[2], a1[3]};
                    *(short4v*)&As[2][sm][col] = (short4v){a2[0], a2[1], a2[2], a2[3]};
                }
            }
        } else {
            const float* src = alpha + (size_t)(k0 + skk) * N + i0 + sc0;
#pragma unroll
            for (int q = 0; q < 4; q++) {
                float4 v = f4c(src)[q];
                float vv[4] = {v.x, v.y, v.z, v.w};
#pragma unroll
                for (int e = 0; e < 4; e++) {
                    int m = sc0 + 4 * q + e;
                    int swz = (m >> 4) & 3;
                    int col = (skk & 7) | ((((skk >> 3) ^ swz)) << 3);
                    short tmp[3];
                    splitN<NS>(vv[e], tmp);
                    As[0][m][col] = tmp[0];
                    if constexpr (NTERMS > 1) { As[1][m][col] = tmp[1]; As[2][m][col] = tmp[2]; }
                }
            }
        }
        {
            const float* src = Bsrc + (size_t)(k0 + skk) * D + sc0;
#pragma unroll
            for (int q = 0; q < 4; q++) {
                float4 v = f4c(src)[q];
                float vv[4] = {v.x, v.y, v.z, v.w};
#pragma unroll
                for (int e = 0; e < 4; e++) {
                    int n = sc0 + 4 * q + e;
                    int swz = (n >> 4) & 3;
                    int col = (skk & 7) | ((((skk >> 3) ^ swz)) << 3);
                    short tmp[3];
                    splitN<NS>(vv[e], tmp);
                    Bs[0][n][col] = tmp[0];
                    if constexpr (NTERMS > 1) { Bs[1][n][col] = tmp[1]; Bs[2][n][col] = tmp[2]; }
                }
            }
        }
        __syncthreads();
        short8v af[NS][4], bg[NS][4];
#pragma unroll
        for (int mr = 0; mr < 4; mr++) {
            int row = wm * 64 + mr * 16 + fr;
            int cidx = 8 * (fq ^ ((wm * 4 + mr) & 3));
#pragma unroll
            for (int s = 0; s < NS; s++) af[s][mr] = *(const short8v*)&As[s][row][cidx];
        }
#pragma unroll
        for (int nr = 0; nr < 4; nr++) {
            int rowb = wn * 64 + nr * 16 + fr;
            int cidx = 8 * (fq ^ ((wn * 4 + nr) & 3));
#pragma unroll
            for (int s = 0; s < NS; s++) bg[s][nr] = *(const short8v*)&Bs[s][rowb][cidx];
        }
#pragma unroll
        for (int mr = 0; mr < 4; mr++) {
#pragma unroll
            for (int nr = 0; nr < 4; nr++) {
                f32x4 a = acc[mr][nr];
                a = __builtin_amdgcn_mfma_f32_16x16x32_bf16(af[0][mr], bg[0][nr], a, 0, 0, 0);
                if constexpr (NTERMS > 1) {
                    a = __builtin_amdgcn_mfma_f32_16x16x32_bf16(af[0][mr], bg[1][nr], a, 0, 0, 0);
                    a = __builtin_amdgcn_mfma_f32_16x16x32_bf16(af[1][mr], bg[0][nr], a, 0, 0, 0);
                    a = __builtin_amdgcn_mfma_f32_16x16x32_bf16(af[1][mr], bg[1][nr], a, 0, 0, 0);
                    a = __builtin_amdgcn_mfma_f32_16x16x32_bf16(af[0][mr], bg[2][nr], a, 0, 0, 0);
                    a = __builtin_amdgcn_mfma_f32_16x16x32_bf16(af[2][mr], bg[0][nr], a, 0, 0, 0);
                }
                acc[mr][nr] = a;
            }
        }
        __syncthreads();
    }
#pragma unroll
    for (int mr = 0; mr < 4; mr++) {
#pragma unroll
        for (int nr = 0; nr < 4; nr++) {
            int col = bx * 128 + wn * 64 + nr * 16 + fr;
#pragma unroll
            for (int j = 0; j < 4; j++) {
                int row = i0 + wm * 64 + mr * 16 + fq * 4 + j;
                out[(size_t)row * 512 + col] = acc[mr][nr][j];
            }
        }
    }
}

// ---------------------------------------------------------------------------
__global__ __launch_bounds__(256) void rowdot_kernel(const float* __restrict__ X,
                                                     const float* __restrict__ v,
                                                     float* __restrict__ out) {
    int lane = threadIdx.x & 63;
    int row = blockIdx.x * 4 + (threadIdx.x >> 6);
    float4 a = f4c(X + (size_t)row * D)[lane];
    float4 b = f4c(v)[lane];
    float s = a.x * b.x + a.y * b.y + a.z * b.z + a.w * b.w;
#pragma unroll
    for (int off = 32; off > 0; off >>= 1) s += __shfl_down(s, off);
    if (lane == 0) out[row] = s;
}

__global__ __launch_bounds__(256) void gemm_nk256_kernel(const float* __restrict__ A,
                                                         const float* __restrict__ W,
                                                         float* __restrict__ C) {
    __shared__ float As[16][68];
    __shared__ float Bs[16][68];
    int t = threadIdx.x;
    int tx = t & 15, ty = t >> 4;
    int j0 = blockIdx.x * 64;
    int i0 = blockIdx.y * 64;
    float acc[4][4] = {};
    for (int k0 = 0; k0 < 256; k0 += 16) {
        {
            int m = t >> 2, k4 = (t & 3) * 4;
            float4 a = *f4c(A + (size_t)(i0 + m) * D + k0 + k4);
            As[k4 + 0][m] = a.x; As[k4 + 1][m] = a.y; As[k4 + 2][m] = a.z; As[k4 + 3][m] = a.w;
            int kk = t >> 4, c = (t & 15) * 4;
            *f4(&Bs[kk][c]) = *f4c(W + (size_t)(k0 + kk) * D + j0 + c);
        }
        __syncthreads();
#pragma unroll
        for (int kk = 0; kk < 16; kk++) {
            float4 av = *f4c(&As[kk][ty * 4]);
            float4 bv = *f4c(&Bs[kk][tx * 4]);
            float a[4] = {av.x, av.y, av.z, av.w};
            float b[4] = {bv.x, bv.y, bv.z, bv.w};
#pragma unroll
            for (int r = 0; r < 4; r++)
#pragma unroll
                for (int c = 0; c < 4; c++) acc[r][c] = fmaf(a[r], b[c], acc[r][c]);
        }
        __syncthreads();
    }
#pragma unroll
    for (int r = 0; r < 4; r++) {
        float4 o = {acc[r][0], acc[r][1], acc[r][2], acc[r][3]};
        *f4(C + (size_t)(i0 + ty * 4 + r) * D + j0 + tx * 4) = o;
    }
}

__global__ __launch_bounds__(256) void update_kernel(const float* __restrict__ A1,
                                                     const float* __restrict__ W1,
                                                     const float* __restrict__ A2,
                                                     const float* __restrict__ W2,
                                                     float* __restrict__ C) {
    __shared__ float As[16][68];
    __shared__ float Bs[16][68];
    int t = threadIdx.x;
    int tx = t & 15, ty = t >> 4;
    int j0 = blockIdx.x * 64;
    int i0 = blockIdx.y * 64;
    float acc[4][4] = {};
#pragma unroll 1
    for (int pass = 0; pass < 2; pass++) {
        const float* Ap = pass ? A2 : A1;
        const float* Wp = pass ? W2 : W1;
        for (int k0 = 0; k0 < 256; k0 += 16) {
            {
                int m = t >> 2, k4 = (t & 3) * 4;
                float4 a = *f4c(Ap + (size_t)(i0 + m) * D + k0 + k4);
                As[k4 + 0][m] = a.x; As[k4 + 1][m] = a.y; As[k4 + 2][m] = a.z; As[k4 + 3][m] = a.w;
                int kk = t >> 4, c = (t & 15) * 4;
                *f4(&Bs[kk][c]) = *f4c(Wp + (size_t)(k0 + kk) * D + j0 + c);
            }
            __syncthreads();
#pragma unroll
            for (int kk = 0; kk < 16; kk++) {
                float4 av = *f4c(&As[kk][ty * 4]);
                float4 bv = *f4c(&Bs[kk][tx * 4]);
                float a[4] = {av.x, av.y, av.z, av.w};
                float b[4] = {bv.x, bv.y, bv.z, bv.w};
#pragma unroll
                for (int r = 0; r < 4; r++)
#pragma unroll
                    for (int c = 0; c < 4; c++) acc[r][c] = fmaf(a[r], b[c], acc[r][c]);
            }
            __syncthreads();
        }
    }
#pragma unroll
    for (int r = 0; r < 4; r++) {
        float o[4];
#pragma unroll
        for (int c = 0; c < 4; c++) {
            float x = acc[r][c];
            o[c] = x >= 0.f ? x : 0.1f * x;
        }
        float4 ov = {o[0], o[1], o[2], o[3]};
        *f4(C + (size_t)(i0 + ty * 4 + r) * D + j0 + tx * 4) = ov;
    }
}

__global__ __launch_bounds__(256) void logits_kernel(const float* __restrict__ Z,
                                                     const float* __restrict__ Dp,
                                                     const float* __restrict__ bh,
                                                     const float* __restrict__ bd,
                                                     float* __restrict__ alpha) {
    __shared__ float As[32][132];
    __shared__ float Bs[32][132];
    int t = threadIdx.x;
    int tx = t & 15, ty = t >> 4;
    int j0 = blockIdx.x * 128;
    int i0 = blockIdx.y * 128;
    float acc[8][8] = {};
    for (int k0 = 0; k0 < 256; k0 += 32) {
#pragma unroll
        for (int r = 0; r < 4; r++) {
            int fid = r * 256 + t;
            int m = fid >> 3, k4 = (fid & 7) * 4;
            float4 a = *f4c(Z + (size_t)(i0 + m) * D + k0 + k4);
            As[k4 + 0][m] = a.x; As[k4 + 1][m] = a.y; As[k4 + 2][m] = a.z; As[k4 + 3][m] = a.w;
            float4 b = *f4c(Dp + (size_t)(j0 + m) * D + k0 + k4);
            Bs[k4 + 0][m] = b.x; Bs[k4 + 1][m] = b.y; Bs[k4 + 2][m] = b.z; Bs[k4 + 3][m] = b.w;
        }
        __syncthreads();
#pragma unroll 4
        for (int kk = 0; kk < 32; kk++) {
            float4 a0 = *f4c(&As[kk][ty * 8]);
            float4 a1 = *f4c(&As[kk][ty * 8 + 4]);
            float4 b0 = *f4c(&Bs[kk][tx * 8]);
            float4 b1 = *f4c(&Bs[kk][tx * 8 + 4]);
            float a[8] = {a0.x, a0.y, a0.z, a0.w, a1.x, a1.y, a1.z, a1.w};
            float b[8] = {b0.x, b0.y, b0.z, b0.w, b1.x, b1.y, b1.z, b1.w};
#pragma unroll
            for (int r = 0; r < 8; r++)
#pragma unroll
                for (int c = 0; c < 8; c++) acc[r][c] = fmaf(a[r], b[c], acc[r][c]);
        }
        __syncthreads();
    }
    float4 bd0 = *f4c(bd + j0 + tx * 8);
    float4 bd1 = *f4c(bd + j0 + tx * 8 + 4);
#pragma unroll
    for (int r = 0; r < 8; r++) {
        float bhr = bh[i0 + ty * 8 + r];
        float4 o0 = {acc[r][0] + bhr + bd0.x, acc[r][1] + bhr + bd0.y,
                     acc[r][2] + bhr + bd0.z, acc[r][3] + bhr + bd0.w};
        float4 o1 = {acc[r][4] + bhr + bd1.x, acc[r][5] + bhr + bd1.y,
                     acc[r][6] + bhr + bd1.z, acc[r][7] + bhr + bd1.w};
        float* orow = alpha + (size_t)(i0 + ty * 8 + r) * N + j0 + tx * 8;
        f4(orow)[0] = o0;
        f4(orow)[1] = o1;
    }
}

__global__ __launch_bounds__(256) void softmax_kernel(float* __restrict__ alpha) {
    int row = blockIdx.x;
    int t = threadIdx.x;
    float4* rp = f4(alpha + (size_t)row * N);
    float4 v[8];
    float m = -3.4e38f;
#pragma unroll
    for (int i = 0; i < 8; i++) {
        v[i] = rp[i * 256 + t];
        m = fmaxf(m, fmaxf(fmaxf(v[i].x, v[i].y), fmaxf(v[i].z, v[i].w)));
    }
    __shared__ float red[8];
#pragma unroll
    for (int off = 32; off > 0; off >>= 1) m = fmaxf(m, __shfl_xor(m, off));
    if ((t & 63) == 0) red[t >> 6] = m;
    __syncthreads();
    m = fmaxf(fmaxf(red[0], red[1]), fmaxf(red[2], red[3]));
    float s = 0.f;
#pragma unroll
    for (int i = 0; i < 8; i++) {
        v[i].x = __expf(v[i].x - m);
        v[i].y = __expf(v[i].y - m);
        v[i].z = __expf(v[i].z - m);
        v[i].w = __expf(v[i].w - m);
        s += v[i].x + v[i].y + v[i].z + v[i].w;
    }
#pragma unroll
    for (int off = 32; off > 0; off >>= 1) s += __shfl_xor(s, off);
    if ((t & 63) == 0) red[4 + (t >> 6)] = s;
    __syncthreads();
    s = red[4] + red[5] + red[6] + red[7];
    float inv = 1.f / s;
#pragma unroll
    for (int i = 0; i < 8; i++) {
        v[i].x *= inv; v[i].y *= inv; v[i].z *= inv; v[i].w *= inv;
        rp[i * 256 + t] = v[i];
    }
}

__global__ __launch_bounds__(256) void diag_kernel(const float* __restrict__ alpha,
                                                   float* __restrict__ da) {
    int i = blockIdx.x * 256 + threadIdx.x;
    da[i] = alpha[(size_t)i * N + i];
}

__global__ __launch_bounds__(256) void combine_kernel(const float* __restrict__ S,
                                                      const float* __restrict__ T,
                                                      const float* __restrict__ da,
                                                      const float* __restrict__ H,
                                                      const float* __restrict__ Dp,
                                                      float* __restrict__ hagg,
                                                      float* __restrict__ dagg) {
    int gid = blockIdx.x * 256 + threadIdx.x;
    int i = gid >> 6;
    int d4 = (gid & 63) * 4;
    float a = da[i];
    float4 sH = *f4c(S + (size_t)i * (2 * D) + d4);
    float4 sD = *f4c(S + (size_t)i * (2 * D) + D + d4);
    float4 tH = *f4c(T + (size_t)i * (2 * D) + d4);
    float4 tD = *f4c(T + (size_t)i * (2 * D) + D + d4);
    float4 h = *f4c(H + (size_t)i * D + d4);
    float4 dp = *f4c(Dp + (size_t)i * D + d4);
    float4 hd = {h.x + dp.x, h.y + dp.y, h.z + dp.z, h.w + dp.w};
    float4 ha = {tH.x + sD.x - a * hd.x, tH.y + sD.y - a * hd.y,
                 tH.z + sD.z - a * hd.z, tH.w + sD.w - a * hd.w};
    float4 dg = {sH.x + tD.x - a * hd.x, sH.y + tD.y - a * hd.y,
                 sH.z + tD.z - a * hd.z, sH.w + tD.w - a * hd.w};
    *f4(hagg + (size_t)i * D + d4) = ha;
    *f4(dagg + (size_t)i * D + d4) = dg;
}

extern "C" void kernel_launch(void* const* d_in, const int* in_sizes, int n_in,
                              void* d_out, int out_size, void* d_ws, size_t ws_size,
                              hipStream_t stream) {
    const float* head = (const float*)d_in[0];
    const float* dep = (const float*)d_in[1];
    const float* tpA[2] = {(const float*)d_in[2], (const float*)d_in[5]};
    const float* tpb1[2] = {(const float*)d_in[3], (const float*)d_in[6]};
    const float* tpb2[2] = {(const float*)d_in[4], (const float*)d_in[7]};
    const float* awh[2] = {(const float*)d_in[8], (const float*)d_in[12]};
    const float* awd[2] = {(const float*)d_in[9], (const float*)d_in[13]};
    const float* cwh[2] = {(const float*)d_in[10], (const float*)d_in[14]};
    const float* cwd[2] = {(const float*)d_in[11], (const float*)d_in[15]};

    float* out = (float*)d_out;
    float* outHead = out;
    float* outDep = out + (size_t)N * D;
    float* alpha1 = out + (size_t)2 * N * D;
    float* alpha2 = alpha1 + (size_t)N * N;

    float* w = (float*)d_ws;
    float* S = w;               w += (size_t)N * 2 * D;
    float* Z = S;               // overlay, disjoint lifetime
    float* T = w;               w += (size_t)N * 2 * D;
    float* bh = w;              w += N;
    float* bd = w;              w += N;
    float* da = w;              w += N;
    float* hagg = w;            w += (size_t)N * D;
    float* dagg = w;            w += (size_t)N * D;
    float* H1 = w;              w += (size_t)N * D;
    float* D1 = w;              w += (size_t)N * D;
    float* alphaT = w;          w += (size_t)N * N;
    size_t needed = ((char*)w) - (char*)d_ws;
    const bool use_sparse = (ws_size >= needed);

    for (int L = 0; L < 2; L++) {
        const float* Hin = L ? H1 : head;
        const float* Din = L ? D1 : dep;
        float* Hout = L ? outHead : H1;
        float* Dout = L ? outDep : D1;
        float* alpha = L ? alpha2 : alpha1;

        rowdot_kernel<<<N / 4, 256, 0, stream>>>(Hin, tpb1[L], bh);
        rowdot_kernel<<<N / 4, 256, 0, stream>>>(Din, tpb2[L], bd);
        gemm_nk256_kernel<<<dim3(D / 64, N / 64), 256, 0, stream>>>(Hin, tpA[L], Z);
        logits_kernel<<<dim3(N / 128, N / 128), 256, 0, stream>>>(Z, Din, bh, bd, alpha);
        softmax_kernel<<<N, 256, 0, stream>>>(alpha);
        diag_kernel<<<N / 256, 256, 0, stream>>>(alpha, da);
        if (use_sparse) {
            transpose_kernel<<<dim3(N / 64, N / 64), 256, 0, stream>>>(alpha, alphaT);
            spmm_scan8<<<dim3(N, 2), 512, 0, stream>>>(alpha, alphaT, Hin, Din, S, T);
        } else {
            if (L == 0) {
                agg_mfma<6, 0><<<dim3(4, N / 128), 256, 0, stream>>>(alpha, Hin, Din, S);
                agg_mfma<6, 1><<<dim3(4, N / 128), 256, 0, stream>>>(alpha, Hin, Din, T);
            } else {
                agg_mfma<1, 0><<<dim3(4, N / 128), 256, 0, stream>>>(alpha, Hin, Din, S);
                agg_mfma<1, 1><<<dim3(4, N / 128), 256, 0, stream>>>(alpha, Hin, Din, T);
            }
        }
        combine_kernel<<<(N * D / 4) / 256, 256, 0, stream>>>(S, T, da, Hin, Din, hagg, dagg);
        update_kernel<<<dim3(D / 64, N / 64), 256, 0, stream>>>(hagg, awh[L], Hin, cwh[L], Hout);
        update_kernel<<<dim3(D / 64, N / 64), 256, 0, stream>>>(dagg, awd[L], Din, cwd[L], Dout);
    }
}

// Round 6
// 1635.484 us; speedup vs baseline: 2.7476x; 1.2480x over previous
//
#include <hip/hip_runtime.h>

constexpr int N = 8192;
constexpr int D = 256;

typedef __attribute__((ext_vector_type(8))) short short8v;
typedef __attribute__((ext_vector_type(4))) short short4v;
typedef __attribute__((ext_vector_type(4))) float f32x4;

__device__ __forceinline__ const float4* f4c(const float* p) { return reinterpret_cast<const float4*>(p); }
__device__ __forceinline__ float4* f4(float* p) { return reinterpret_cast<float4*>(p); }

__device__ __forceinline__ short f2bf(float f) {
    unsigned u = __builtin_bit_cast(unsigned, f);
    u += 0x7fff + ((u >> 16) & 1);
    return (short)(u >> 16);
}
__device__ __forceinline__ float bf2f(short s) {
    unsigned u = ((unsigned)(unsigned short)s) << 16;
    return __builtin_bit_cast(float, u);
}
// up-to-3-limb exact bf16 split (s may have space for 3; limbs beyond NS-1 unused)
template <int NS>
__device__ __forceinline__ void splitN(float x, short* s) {
    s[0] = f2bf(x);
    if constexpr (NS > 1) {
        float r = x - bf2f(s[0]);
        s[1] = f2bf(r);
        s[2] = f2bf(r - bf2f(s[1]));
    }
}

// ===========================================================================
// split an [N x 256] fp32 matrix into NL bf16 limb planes (same layout)
// ===========================================================================
template <int NL>
__global__ __launch_bounds__(256) void split_limbs(const float* __restrict__ src,
                                                   unsigned short* __restrict__ dst) {
    const size_t ND = (size_t)N * D;
    int gid = blockIdx.x * 256 + threadIdx.x;  // 8 elems/thread
    float4 v0 = f4c(src)[gid * 2];
    float4 v1 = f4c(src)[gid * 2 + 1];
    float vv[8] = {v0.x, v0.y, v0.z, v0.w, v1.x, v1.y, v1.z, v1.w};
    short sp[3][8];
#pragma unroll
    for (int e = 0; e < 8; e++) {
        short tmp[3];
        splitN<NL>(vv[e], tmp);
        sp[0][e] = tmp[0];
        if constexpr (NL > 1) { sp[1][e] = tmp[1]; sp[2][e] = tmp[2]; }
    }
#pragma unroll
    for (int s = 0; s < NL; s++)
        *(short8v*)(dst + s * ND + (size_t)gid * 8) =
            (short8v){sp[s][0], sp[s][1], sp[s][2], sp[s][3],
                      sp[s][4], sp[s][5], sp[s][6], sp[s][7]};
}

// ===========================================================================
// logits via MFMA limb planes: alpha[i,j] = sum_d Z[i,d]*Dp[j,d] + bh[i] + bd[j]
// zP/dP: [NL][N][256] bf16 limb planes. NPROD=3 (layer1) or 6 (layer2/fp32-grade).
// 128x128 tile, 4 waves 2x2, BK=32, XOR-swizzled LDS (same proven geometry).
// ===========================================================================
template <int NL, int NPROD>
__global__ __launch_bounds__(256, 2)
void logits_mfma(const unsigned short* __restrict__ zP,
                 const unsigned short* __restrict__ dP,
                 const float* __restrict__ bh, const float* __restrict__ bd,
                 float* __restrict__ alpha) {
    __shared__ unsigned short As[NL][128][40];
    __shared__ unsigned short Bs[NL][128][40];
    const int t = threadIdx.x;
    const int j0 = blockIdx.x * 128;
    const int i0 = blockIdx.y * 128;
    const size_t PS = (size_t)N * D;
    const int lane = t & 63, w = t >> 6, wm = w >> 1, wn = w & 1;
    const int fr = lane & 15, fq = lane >> 4;

    f32x4 acc[4][4];
#pragma unroll
    for (int a = 0; a < 4; a++)
#pragma unroll
        for (int b = 0; b < 4; b++) acc[a][b] = (f32x4){0.f, 0.f, 0.f, 0.f};

#pragma unroll 1
    for (int k0 = 0; k0 < D; k0 += 32) {
#pragma unroll
        for (int s = 0; s < NL; s++) {
#pragma unroll
            for (int g = 0; g < 2; g++) {
                int gid = g * 256 + t;
                int m = gid >> 2, gk = gid & 3;
                int col = (gk ^ ((m >> 4) & 3)) << 3;
                short8v va = *(const short8v*)(zP + s * PS + (size_t)(i0 + m) * D + k0 + gk * 8);
                *(short8v*)&As[s][m][col] = va;
                short8v vb = *(const short8v*)(dP + s * PS + (size_t)(j0 + m) * D + k0 + gk * 8);
                *(short8v*)&Bs[s][m][col] = vb;
            }
        }
        __syncthreads();

        short8v af[NL][4], bg[NL][4];
#pragma unroll
        for (int mr = 0; mr < 4; mr++) {
            int row = wm * 64 + mr * 16 + fr;
            int cidx = 8 * (fq ^ ((wm * 4 + mr) & 3));
#pragma unroll
            for (int s = 0; s < NL; s++) af[s][mr] = *(const short8v*)&As[s][row][cidx];
        }
#pragma unroll
        for (int nr = 0; nr < 4; nr++) {
            int rowb = wn * 64 + nr * 16 + fr;
            int cidx = 8 * (fq ^ ((wn * 4 + nr) & 3));
#pragma unroll
            for (int s = 0; s < NL; s++) bg[s][nr] = *(const short8v*)&Bs[s][rowb][cidx];
        }
#pragma unroll
        for (int mr = 0; mr < 4; mr++) {
#pragma unroll
            for (int nr = 0; nr < 4; nr++) {
                f32x4 a = acc[mr][nr];
                a = __builtin_amdgcn_mfma_f32_16x16x32_bf16(af[0][mr], bg[0][nr], a, 0, 0, 0);
                if constexpr (NPROD >= 3) {
                    a = __builtin_amdgcn_mfma_f32_16x16x32_bf16(af[0][mr], bg[1][nr], a, 0, 0, 0);
                    a = __builtin_amdgcn_mfma_f32_16x16x32_bf16(af[1][mr], bg[0][nr], a, 0, 0, 0);
                }
                if constexpr (NPROD >= 6) {
                    a = __builtin_amdgcn_mfma_f32_16x16x32_bf16(af[1][mr], bg[1][nr], a, 0, 0, 0);
                    a = __builtin_amdgcn_mfma_f32_16x16x32_bf16(af[0][mr], bg[2][nr], a, 0, 0, 0);
                    a = __builtin_amdgcn_mfma_f32_16x16x32_bf16(af[2][mr], bg[0][nr], a, 0, 0, 0);
                }
                acc[mr][nr] = a;
            }
        }
        __syncthreads();
    }

#pragma unroll
    for (int nr = 0; nr < 4; nr++) {
        int col = j0 + wn * 64 + nr * 16 + fr;
        float bdv = bd[col];
#pragma unroll
        for (int mr = 0; mr < 4; mr++) {
#pragma unroll
            for (int j = 0; j < 4; j++) {
                int row = i0 + wm * 64 + mr * 16 + fq * 4 + j;
                alpha[(size_t)row * N + col] = acc[mr][nr][j] + bh[row] + bdv;
            }
        }
    }
}

// ===========================================================================
// Sparse aggregation (round-5 proven). alpha post-softmax is >99% exact zeros.
// ===========================================================================
__global__ __launch_bounds__(512) void spmm_scan8(const float* __restrict__ M0,
                                                  const float* __restrict__ M1,
                                                  const float* __restrict__ H,
                                                  const float* __restrict__ Dp,
                                                  float* __restrict__ S,
                                                  float* __restrict__ T) {
    const float* __restrict__ M = blockIdx.y ? M1 : M0;
    float* __restrict__ out = blockIdx.y ? T : S;
    const int row = blockIdx.x;
    const int w = threadIdx.x >> 6;
    const int lane = threadIdx.x & 63;
    const float* __restrict__ src = (lane < 32) ? H : Dp;
    const int c0 = (lane & 31) * 8;

    const float4* rp = f4c(M + (size_t)row * N) + w * 256;
    float4 v[4];
#pragma unroll
    for (int q = 0; q < 4; q++) v[q] = rp[q * 64 + lane];

    float4 acc0 = {0.f, 0.f, 0.f, 0.f}, acc1 = {0.f, 0.f, 0.f, 0.f};
#pragma unroll
    for (int q = 0; q < 4; q++) {
        float va[4] = {v[q].x, v[q].y, v[q].z, v[q].w};
#pragma unroll
        for (int e = 0; e < 4; e++) {
            unsigned long long mask = __ballot(va[e] != 0.0f);
            while (mask) {
                int l = __builtin_ctzll(mask);
                mask &= mask - 1;
                float a = __shfl(va[e], l);
                int j = w * 1024 + q * 256 + l * 4 + e;
                const float* xr = src + (size_t)j * D + c0;
                float4 x0 = *f4c(xr);
                float4 x1 = *f4c(xr + 4);
                acc0.x = fmaf(a, x0.x, acc0.x);
                acc0.y = fmaf(a, x0.y, acc0.y);
                acc0.z = fmaf(a, x0.z, acc0.z);
                acc0.w = fmaf(a, x0.w, acc0.w);
                acc1.x = fmaf(a, x1.x, acc1.x);
                acc1.y = fmaf(a, x1.y, acc1.y);
                acc1.z = fmaf(a, x1.z, acc1.z);
                acc1.w = fmaf(a, x1.w, acc1.w);
            }
        }
    }

    __shared__ float part[8][512];
    const int colbase = c0 + ((lane < 32) ? 0 : 256);
    *f4(&part[w][colbase]) = acc0;
    *f4(&part[w][colbase + 4]) = acc1;
    __syncthreads();
    const int t = threadIdx.x;
    float s = 0.f;
#pragma unroll
    for (int ww = 0; ww < 8; ww++) s += part[ww][t];
    out[(size_t)row * 512 + t] = s;
}

// 64x64 LDS tile transpose
__global__ __launch_bounds__(256) void transpose_kernel(const float* __restrict__ in,
                                                        float* __restrict__ outT) {
    __shared__ float tile[64][65];
    const int t = threadIdx.x;
    const int i0 = blockIdx.y * 64;
    const int j0 = blockIdx.x * 64;
    const int r = t >> 2;
    const int c0 = (t & 3) * 16;
#pragma unroll
    for (int q = 0; q < 4; q++) {
        float4 v = *f4c(in + (size_t)(i0 + r) * N + j0 + c0 + q * 4);
        tile[r][c0 + q * 4 + 0] = v.x;
        tile[r][c0 + q * 4 + 1] = v.y;
        tile[r][c0 + q * 4 + 2] = v.z;
        tile[r][c0 + q * 4 + 3] = v.w;
    }
    __syncthreads();
#pragma unroll
    for (int q = 0; q < 4; q++) {
        float4 o = {tile[c0 + q * 4 + 0][r], tile[c0 + q * 4 + 1][r],
                    tile[c0 + q * 4 + 2][r], tile[c0 + q * 4 + 3][r]};
        *f4(outT + (size_t)(j0 + r) * N + i0 + c0 + q * 4) = o;
    }
}

// ===========================================================================
// FALLBACK dense agg (round-2 proven)
// ===========================================================================
template <int NTERMS, int TRANS>
__global__ __launch_bounds__(256, NTERMS == 1 ? 3 : 2)
void agg_mfma(const float* __restrict__ alpha, const float* __restrict__ H,
              const float* __restrict__ Dp, float* __restrict__ out) {
    constexpr int NS = (NTERMS == 1) ? 1 : 3;
    __shared__ short As[NS][128][40];
    __shared__ short Bs[NS][128][40];
    const int t = threadIdx.x;
    const int bx = blockIdx.x;
    const int i0 = blockIdx.y * 128;
    const float* Bsrc = (bx < 2) ? (H + bx * 128) : (Dp + (bx - 2) * 128);
    const int lane = t & 63;
    const int w = t >> 6;
    const int wm = w >> 1, wn = w & 1;
    const int fr = lane & 15, fq = lane >> 4;
    f32x4 acc[4][4];
#pragma unroll
    for (int a = 0; a < 4; a++)
#pragma unroll
        for (int b = 0; b < 4; b++) acc[a][b] = (f32x4){0.f, 0.f, 0.f, 0.f};
    const int sm = t >> 1;
    const int skh = (t & 1) << 4;
    const int skk = t >> 3;
    const int sc0 = (t & 7) << 4;
#pragma unroll 1
    for (int k0 = 0; k0 < N; k0 += 32) {
        if constexpr (TRANS == 0) {
            const float* src = alpha + (size_t)(i0 + sm) * N + k0 + skh;
            const int swz = (sm >> 4) & 3;
#pragma unroll
            for (int q = 0; q < 4; q++) {
                float4 v = f4c(src)[q];
                int k = skh + 4 * q;
                int col = ((((k >> 3) ^ swz)) << 3) | (k & 4);
                float vv[4] = {v.x, v.y, v.z, v.w};
                short a0[4], a1[4], a2[4];
#pragma unroll
                for (int e = 0; e < 4; e++) {
                    short tmp[3];
                    splitN<NS>(vv[e], tmp);
                    a0[e] = tmp[0]; a1[e] = tmp[1]; a2[e] = tmp[2];
                }
                *(short4v*)&As[0][sm][col] = (short4v){a0[0], a0[1], a0[2], a0[3]};
                if constexpr (NTERMS > 1) {
                    *(short4v*)&As[1][sm][col] = (short4v){a1[0], a1[1], a1[2], a1[3]};
                    *(short4v*)&As[2][sm][col] = (short4v){a2[0], a2[1], a2[2], a2[3]};
                }
            }
        } else {
            const float* src = alpha + (size_t)(k0 + skk) * N + i0 + sc0;
#pragma unroll
            for (int q = 0; q < 4; q++) {
                float4 v = f4c(src)[q];
                float vv[4] = {v.x, v.y, v.z, v.w};
#pragma unroll
                for (int e = 0; e < 4; e++) {
                    int m = sc0 + 4 * q + e;
                    int swz = (m >> 4) & 3;
                    int col = (skk & 7) | ((((skk >> 3) ^ swz)) << 3);
                    short tmp[3];
                    splitN<NS>(vv[e], tmp);
                    As[0][m][col] = tmp[0];
                    if constexpr (NTERMS > 1) { As[1][m][col] = tmp[1]; As[2][m][col] = tmp[2]; }
                }
            }
        }
        {
            const float* src = Bsrc + (size_t)(k0 + skk) * D + sc0;
#pragma unroll
            for (int q = 0; q < 4; q++) {
                float4 v = f4c(src)[q];
                float vv[4] = {v.x, v.y, v.z, v.w};
#pragma unroll
                for (int e = 0; e < 4; e++) {
                    int n = sc0 + 4 * q + e;
                    int swz = (n >> 4) & 3;
                    int col = (skk & 7) | ((((skk >> 3) ^ swz)) << 3);
                    short tmp[3];
                    splitN<NS>(vv[e], tmp);
                    Bs[0][n][col] = tmp[0];
                    if constexpr (NTERMS > 1) { Bs[1][n][col] = tmp[1]; Bs[2][n][col] = tmp[2]; }
                }
            }
        }
        __syncthreads();
        short8v af[NS][4], bg[NS][4];
#pragma unroll
        for (int mr = 0; mr < 4; mr++) {
            int row = wm * 64 + mr * 16 + fr;
            int cidx = 8 * (fq ^ ((wm * 4 + mr) & 3));
#pragma unroll
            for (int s = 0; s < NS; s++) af[s][mr] = *(const short8v*)&As[s][row][cidx];
        }
#pragma unroll
        for (int nr = 0; nr < 4; nr++) {
            int rowb = wn * 64 + nr * 16 + fr;
            int cidx = 8 * (fq ^ ((wn * 4 + nr) & 3));
#pragma unroll
            for (int s = 0; s < NS; s++) bg[s][nr] = *(const short8v*)&Bs[s][rowb][cidx];
        }
#pragma unroll
        for (int mr = 0; mr < 4; mr++) {
#pragma unroll
            for (int nr = 0; nr < 4; nr++) {
                f32x4 a = acc[mr][nr];
                a = __builtin_amdgcn_mfma_f32_16x16x32_bf16(af[0][mr], bg[0][nr], a, 0, 0, 0);
                if constexpr (NTERMS > 1) {
                    a = __builtin_amdgcn_mfma_f32_16x16x32_bf16(af[0][mr], bg[1][nr], a, 0, 0, 0);
                    a = __builtin_amdgcn_mfma_f32_16x16x32_bf16(af[1][mr], bg[0][nr], a, 0, 0, 0);
                    a = __builtin_amdgcn_mfma_f32_16x16x32_bf16(af[1][mr], bg[1][nr], a, 0, 0, 0);
                    a = __builtin_amdgcn_mfma_f32_16x16x32_bf16(af[0][mr], bg[2][nr], a, 0, 0, 0);
                    a = __builtin_amdgcn_mfma_f32_16x16x32_bf16(af[2][mr], bg[0][nr], a, 0, 0, 0);
                }
                acc[mr][nr] = a;
            }
        }
        __syncthreads();
    }
#pragma unroll
    for (int mr = 0; mr < 4; mr++) {
#pragma unroll
        for (int nr = 0; nr < 4; nr++) {
            int col = bx * 128 + wn * 64 + nr * 16 + fr;
#pragma unroll
            for (int j = 0; j < 4; j++) {
                int row = i0 + wm * 64 + mr * 16 + fq * 4 + j;
                out[(size_t)row * 512 + col] = acc[mr][nr][j];
            }
        }
    }
}

// ---------------------------------------------------------------------------
__global__ __launch_bounds__(256) void rowdot_kernel(const float* __restrict__ X,
                                                     const float* __restrict__ v,
                                                     float* __restrict__ out) {
    int lane = threadIdx.x & 63;
    int row = blockIdx.x * 4 + (threadIdx.x >> 6);
    float4 a = f4c(X + (size_t)row * D)[lane];
    float4 b = f4c(v)[lane];
    float s = a.x * b.x + a.y * b.y + a.z * b.z + a.w * b.w;
#pragma unroll
    for (int off = 32; off > 0; off >>= 1) s += __shfl_down(s, off);
    if (lane == 0) out[row] = s;
}

__global__ __launch_bounds__(256) void gemm_nk256_kernel(const float* __restrict__ A,
                                                         const float* __restrict__ W,
                                                         float* __restrict__ C) {
    __shared__ float As[16][68];
    __shared__ float Bs[16][68];
    int t = threadIdx.x;
    int tx = t & 15, ty = t >> 4;
    int j0 = blockIdx.x * 64;
    int i0 = blockIdx.y * 64;
    float acc[4][4] = {};
    for (int k0 = 0; k0 < 256; k0 += 16) {
        {
            int m = t >> 2, k4 = (t & 3) * 4;
            float4 a = *f4c(A + (size_t)(i0 + m) * D + k0 + k4);
            As[k4 + 0][m] = a.x; As[k4 + 1][m] = a.y; As[k4 + 2][m] = a.z; As[k4 + 3][m] = a.w;
            int kk = t >> 4, c = (t & 15) * 4;
            *f4(&Bs[kk][c]) = *f4c(W + (size_t)(k0 + kk) * D + j0 + c);
        }
        __syncthreads();
#pragma unroll
        for (int kk = 0; kk < 16; kk++) {
            float4 av = *f4c(&As[kk][ty * 4]);
            float4 bv = *f4c(&Bs[kk][tx * 4]);
            float a[4] = {av.x, av.y, av.z, av.w};
            float b[4] = {bv.x, bv.y, bv.z, bv.w};
#pragma unroll
            for (int r = 0; r < 4; r++)
#pragma unroll
                for (int c = 0; c < 4; c++) acc[r][c] = fmaf(a[r], b[c], acc[r][c]);
        }
        __syncthreads();
    }
#pragma unroll
    for (int r = 0; r < 4; r++) {
        float4 o = {acc[r][0], acc[r][1], acc[r][2], acc[r][3]};
        *f4(C + (size_t)(i0 + ty * 4 + r) * D + j0 + tx * 4) = o;
    }
}

__global__ __launch_bounds__(256) void update_kernel(const float* __restrict__ A1,
                                                     const float* __restrict__ W1,
                                                     const float* __restrict__ A2,
                                                     const float* __restrict__ W2,
                                                     float* __restrict__ C) {
    __shared__ float As[16][68];
    __shared__ float Bs[16][68];
    int t = threadIdx.x;
    int tx = t & 15, ty = t >> 4;
    int j0 = blockIdx.x * 64;
    int i0 = blockIdx.y * 64;
    float acc[4][4] = {};
#pragma unroll 1
    for (int pass = 0; pass < 2; pass++) {
        const float* Ap = pass ? A2 : A1;
        const float* Wp = pass ? W2 : W1;
        for (int k0 = 0; k0 < 256; k0 += 16) {
            {
                int m = t >> 2, k4 = (t & 3) * 4;
                float4 a = *f4c(Ap + (size_t)(i0 + m) * D + k0 + k4);
                As[k4 + 0][m] = a.x; As[k4 + 1][m] = a.y; As[k4 + 2][m] = a.z; As[k4 + 3][m] = a.w;
                int kk = t >> 4, c = (t & 15) * 4;
                *f4(&Bs[kk][c]) = *f4c(Wp + (size_t)(k0 + kk) * D + j0 + c);
            }
            __syncthreads();
#pragma unroll
            for (int kk = 0; kk < 16; kk++) {
                float4 av = *f4c(&As[kk][ty * 4]);
                float4 bv = *f4c(&Bs[kk][tx * 4]);
                float a[4] = {av.x, av.y, av.z, av.w};
                float b[4] = {bv.x, bv.y, bv.z, bv.w};
#pragma unroll
                for (int r = 0; r < 4; r++)
#pragma unroll
                    for (int c = 0; c < 4; c++) acc[r][c] = fmaf(a[r], b[c], acc[r][c]);
            }
            __syncthreads();
        }
    }
#pragma unroll
    for (int r = 0; r < 4; r++) {
        float o[4];
#pragma unroll
        for (int c = 0; c < 4; c++) {
            float x = acc[r][c];
            o[c] = x >= 0.f ? x : 0.1f * x;
        }
        float4 ov = {o[0], o[1], o[2], o[3]};
        *f4(C + (size_t)(i0 + ty * 4 + r) * D + j0 + tx * 4) = ov;
    }
}

// fallback fp32 logits
__global__ __launch_bounds__(256) void logits_kernel(const float* __restrict__ Z,
                                                     const float* __restrict__ Dp,
                                                     const float* __restrict__ bh,
                                                     const float* __restrict__ bd,
                                                     float* __restrict__ alpha) {
    __shared__ float As[32][132];
    __shared__ float Bs[32][132];
    int t = threadIdx.x;
    int tx = t & 15, ty = t >> 4;
    int j0 = blockIdx.x * 128;
    int i0 = blockIdx.y * 128;
    float acc[8][8] = {};
    for (int k0 = 0; k0 < 256; k0 += 32) {
#pragma unroll
        for (int r = 0; r < 4; r++) {
            int fid = r * 256 + t;
            int m = fid >> 3, k4 = (fid & 7) * 4;
            float4 a = *f4c(Z + (size_t)(i0 + m) * D + k0 + k4);
            As[k4 + 0][m] = a.x; As[k4 + 1][m] = a.y; As[k4 + 2][m] = a.z; As[k4 + 3][m] = a.w;
            float4 b = *f4c(Dp + (size_t)(j0 + m) * D + k0 + k4);
            Bs[k4 + 0][m] = b.x; Bs[k4 + 1][m] = b.y; Bs[k4 + 2][m] = b.z; Bs[k4 + 3][m] = b.w;
        }
        __syncthreads();
#pragma unroll 4
        for (int kk = 0; kk < 32; kk++) {
            float4 a0 = *f4c(&As[kk][ty * 8]);
            float4 a1 = *f4c(&As[kk][ty * 8 + 4]);
            float4 b0 = *f4c(&Bs[kk][tx * 8]);
            float4 b1 = *f4c(&Bs[kk][tx * 8 + 4]);
            float a[8] = {a0.x, a0.y, a0.z, a0.w, a1.x, a1.y, a1.z, a1.w};
            float b[8] = {b0.x, b0.y, b0.z, b0.w, b1.x, b1.y, b1.z, b1.w};
#pragma unroll
            for (int r = 0; r < 8; r++)
#pragma unroll
                for (int c = 0; c < 8; c++) acc[r][c] = fmaf(a[r], b[c], acc[r][c]);
        }
        __syncthreads();
    }
    float4 bd0 = *f4c(bd + j0 + tx * 8);
    float4 bd1 = *f4c(bd + j0 + tx * 8 + 4);
#pragma unroll
    for (int r = 0; r < 8; r++) {
        float bhr = bh[i0 + ty * 8 + r];
        float4 o0 = {acc[r][0] + bhr + bd0.x, acc[r][1] + bhr + bd0.y,
                     acc[r][2] + bhr + bd0.z, acc[r][3] + bhr + bd0.w};
        float4 o1 = {acc[r][4] + bhr + bd1.x, acc[r][5] + bhr + bd1.y,
                     acc[r][6] + bhr + bd1.z, acc[r][7] + bhr + bd1.w};
        float* orow = alpha + (size_t)(i0 + ty * 8 + r) * N + j0 + tx * 8;
        f4(orow)[0] = o0;
        f4(orow)[1] = o1;
    }
}

__global__ __launch_bounds__(256) void softmax_kernel(float* __restrict__ alpha) {
    int row = blockIdx.x;
    int t = threadIdx.x;
    float4* rp = f4(alpha + (size_t)row * N);
    float4 v[8];
    float m = -3.4e38f;
#pragma unroll
    for (int i = 0; i < 8; i++) {
        v[i] = rp[i * 256 + t];
        m = fmaxf(m, fmaxf(fmaxf(v[i].x, v[i].y), fmaxf(v[i].z, v[i].w)));
    }
    __shared__ float red[8];
#pragma unroll
    for (int off = 32; off > 0; off >>= 1) m = fmaxf(m, __shfl_xor(m, off));
    if ((t & 63) == 0) red[t >> 6] = m;
    __syncthreads();
    m = fmaxf(fmaxf(red[0], red[1]), fmaxf(red[2], red[3]));
    float s = 0.f;
#pragma unroll
    for (int i = 0; i < 8; i++) {
        v[i].x = __expf(v[i].x - m);
        v[i].y = __expf(v[i].y - m);
        v[i].z = __expf(v[i].z - m);
        v[i].w = __expf(v[i].w - m);
        s += v[i].x + v[i].y + v[i].z + v[i].w;
    }
#pragma unroll
    for (int off = 32; off > 0; off >>= 1) s += __shfl_xor(s, off);
    if ((t & 63) == 0) red[4 + (t >> 6)] = s;
    __syncthreads();
    s = red[4] + red[5] + red[6] + red[7];
    float inv = 1.f / s;
#pragma unroll
    for (int i = 0; i < 8; i++) {
        v[i].x *= inv; v[i].y *= inv; v[i].z *= inv; v[i].w *= inv;
        rp[i * 256 + t] = v[i];
    }
}

__global__ __launch_bounds__(256) void diag_kernel(const float* __restrict__ alpha,
                                                   float* __restrict__ da) {
    int i = blockIdx.x * 256 + threadIdx.x;
    da[i] = alpha[(size_t)i * N + i];
}

__global__ __launch_bounds__(256) void combine_kernel(const float* __restrict__ S,
                                                      const float* __restrict__ T,
                                                      const float* __restrict__ da,
                                                      const float* __restrict__ H,
                                                      const float* __restrict__ Dp,
                                                      float* __restrict__ hagg,
                                                      float* __restrict__ dagg) {
    int gid = blockIdx.x * 256 + threadIdx.x;
    int i = gid >> 6;
    int d4 = (gid & 63) * 4;
    float a = da[i];
    float4 sH = *f4c(S + (size_t)i * (2 * D) + d4);
    float4 sD = *f4c(S + (size_t)i * (2 * D) + D + d4);
    float4 tH = *f4c(T + (size_t)i * (2 * D) + d4);
    float4 tD = *f4c(T + (size_t)i * (2 * D) + D + d4);
    float4 h = *f4c(H + (size_t)i * D + d4);
    float4 dp = *f4c(Dp + (size_t)i * D + d4);
    float4 hd = {h.x + dp.x, h.y + dp.y, h.z + dp.z, h.w + dp.w};
    float4 ha = {tH.x + sD.x - a * hd.x, tH.y + sD.y - a * hd.y,
                 tH.z + sD.z - a * hd.z, tH.w + sD.w - a * hd.w};
    float4 dg = {sH.x + tD.x - a * hd.x, sH.y + tD.y - a * hd.y,
                 sH.z + tD.z - a * hd.z, sH.w + tD.w - a * hd.w};
    *f4(hagg + (size_t)i * D + d4) = ha;
    *f4(dagg + (size_t)i * D + d4) = dg;
}

extern "C" void kernel_launch(void* const* d_in, const int* in_sizes, int n_in,
                              void* d_out, int out_size, void* d_ws, size_t ws_size,
                              hipStream_t stream) {
    const float* head = (const float*)d_in[0];
    const float* dep = (const float*)d_in[1];
    const float* tpA[2] = {(const float*)d_in[2], (const float*)d_in[5]};
    const float* tpb1[2] = {(const float*)d_in[3], (const float*)d_in[6]};
    const float* tpb2[2] = {(const float*)d_in[4], (const float*)d_in[7]};
    const float* awh[2] = {(const float*)d_in[8], (const float*)d_in[12]};
    const float* awd[2] = {(const float*)d_in[9], (const float*)d_in[13]};
    const float* cwh[2] = {(const float*)d_in[10], (const float*)d_in[14]};
    const float* cwd[2] = {(const float*)d_in[11], (const float*)d_in[15]};

    float* out = (float*)d_out;
    float* outHead = out;
    float* outDep = out + (size_t)N * D;
    float* alpha1 = out + (size_t)2 * N * D;
    float* alpha2 = alpha1 + (size_t)N * N;

    float* w = (float*)d_ws;
    float* S = w;               w += (size_t)N * 2 * D;
    float* Z = S;               // overlay, disjoint lifetime
    float* T = w;               w += (size_t)N * 2 * D;
    float* bh = w;              w += N;
    float* bd = w;              w += N;
    float* da = w;              w += N;
    float* hagg = w;            w += (size_t)N * D;
    float* dagg = w;            w += (size_t)N * D;
    float* H1 = w;              w += (size_t)N * D;
    float* D1 = w;              w += (size_t)N * D;
    float* alphaT = w;          w += (size_t)N * N;
    unsigned short* zP = (unsigned short*)w;
    unsigned short* dP = zP + (size_t)3 * N * D;
    size_t needed = ((char*)(dP + (size_t)3 * N * D)) - (char*)d_ws;
    const bool use_fast = (ws_size >= needed);

    for (int L = 0; L < 2; L++) {
        const float* Hin = L ? H1 : head;
        const float* Din = L ? D1 : dep;
        float* Hout = L ? outHead : H1;
        float* Dout = L ? outDep : D1;
        float* alpha = L ? alpha2 : alpha1;

        rowdot_kernel<<<N / 4, 256, 0, stream>>>(Hin, tpb1[L], bh);
        rowdot_kernel<<<N / 4, 256, 0, stream>>>(Din, tpb2[L], bd);
        gemm_nk256_kernel<<<dim3(D / 64, N / 64), 256, 0, stream>>>(Hin, tpA[L], Z);
        if (use_fast) {
            if (L == 0) {
                split_limbs<2><<<N * D / 8 / 256, 256, 0, stream>>>(Z, zP);
                split_limbs<2><<<N * D / 8 / 256, 256, 0, stream>>>(Din, dP);
                logits_mfma<2, 3><<<dim3(N / 128, N / 128), 256, 0, stream>>>(zP, dP, bh, bd, alpha);
            } else {
                split_limbs<3><<<N * D / 8 / 256, 256, 0, stream>>>(Z, zP);
                split_limbs<3><<<N * D / 8 / 256, 256, 0, stream>>>(Din, dP);
                logits_mfma<3, 6><<<dim3(N / 128, N / 128), 256, 0, stream>>>(zP, dP, bh, bd, alpha);
            }
        } else {
            logits_kernel<<<dim3(N / 128, N / 128), 256, 0, stream>>>(Z, Din, bh, bd, alpha);
        }
        softmax_kernel<<<N, 256, 0, stream>>>(alpha);
        diag_kernel<<<N / 256, 256, 0, stream>>>(alpha, da);
        if (use_fast) {
            transpose_kernel<<<dim3(N / 64, N / 64), 256, 0, stream>>>(alpha, alphaT);
            spmm_scan8<<<dim3(N, 2), 512, 0, stream>>>(alpha, alphaT, Hin, Din, S, T);
        } else {
            if (L == 0) {
                agg_mfma<6, 0><<<dim3(4, N / 128), 256, 0, stream>>>(alpha, Hin, Din, S);
                agg_mfma<6, 1><<<dim3(4, N / 128), 256, 0, stream>>>(alpha, Hin, Din, T);
            } else {
                agg_mfma<1, 0><<<dim3(4, N / 128), 256, 0, stream>>>(alpha, Hin, Din, S);
                agg_mfma<1, 1><<<dim3(4, N / 128), 256, 0, stream>>>(alpha, Hin, Din, T);
            }
        }
        combine_kernel<<<(N * D / 4) / 256, 256, 0, stream>>>(S, T, da, Hin, Din, hagg, dagg);
        update_kernel<<<dim3(D / 64, N / 64), 256, 0, stream>>>(hagg, awh[L], Hin, cwh[L], Hout);
        update_kernel<<<dim3(D / 64, N / 64), 256, 0, stream>>>(dagg, awd[L], Din, cwd[L], Dout);
    }
}